// Round 2
// baseline (380.867 us; speedup 1.0000x reference)
//
#include <hip/hip_runtime.h>

// ConvSE3: B=1, N=512, J=48, M=16, MID=128, pairs (di,do) in {0,1}^2.
// Factored algorithm: per-edge MLP -> h2 (ws, fp32);
// per-n: Em[j,q] = mask_j * sum_v basis[u,v,f]*xg[i,v]  (q=(u,i*F+f))
//        S[c,q]  = sum_j h2aug[j,c]*Em[j,q]   (c=128 row = ones, for b3)
//        out[o,u] += sum_{c,k} w3[c, o*KF+k] * S[c, u*KF+k]  / denom  (+ self)
// Avoids materializing R (saves ~8 GFLOP vs direct evaluation).
//
// R2 change: neighbor_masks dtype auto-detection (int32 vs uint8). Block 1 of
// k0_stats scans the buffer as int32; any word >1 => it's uint8. Flag at
// stats[30] selects the read path in k2_pair.

#define EPSV 1e-5f
constexpr int NN  = 512;
constexpr int JJ  = 48;
constexpr int EE  = NN * JJ;   // 24576 edges

// ---------------------------------------------------------------- k0: LN1 stats + mask dtype probe
// h1 = d*w1 + b1 is affine in d, so LN1 mean/var are quadratic in d:
// mu = d*wbar + bbar ; var = d^2*Cw + 2d*Cwb + Cb.
__global__ void k0_stats(const float* __restrict__ w1, const float* __restrict__ b1,
                         const void* __restrict__ nmask, float* __restrict__ stats)
{
    if (blockIdx.x == 1) {
        // mask dtype probe: if int32, first EE/4 words are all 0/1.
        __shared__ int flag;
        if (threadIdx.x == 0) flag = 0;
        __syncthreads();
        const int* m32 = (const int*)nmask;
        int bad = 0;
        for (int i = threadIdx.x; i < EE/4; i += 256) {
            const unsigned v = (unsigned)m32[i];
            if (v > 1u) bad = 1;
        }
        if (bad) flag = 1;
        __syncthreads();
        if (threadIdx.x == 0) stats[30] = flag ? 1.f : 0.f;  // 1 => uint8 layout
        return;
    }
    const int p = threadIdx.x >> 6;     // wave p handles pair p
    const int lane = threadIdx.x & 63;
    const float w0 = w1[p*128 + lane],      b0 = b1[p*128 + lane];
    const float w1v = w1[p*128 + 64 + lane], b1v = b1[p*128 + 64 + lane];
    float sw = w0 + w1v, sb = b0 + b1v;
    float sww = w0*w0 + w1v*w1v, swb = w0*b0 + w1v*b1v, sbb = b0*b0 + b1v*b1v;
    for (int off = 32; off > 0; off >>= 1) {
        sw  += __shfl_down(sw, off);
        sb  += __shfl_down(sb, off);
        sww += __shfl_down(sww, off);
        swb += __shfl_down(swb, off);
        sbb += __shfl_down(sbb, off);
    }
    if (lane == 0) {
        const float wbar = sw * (1.f/128.f), bbar = sb * (1.f/128.f);
        stats[p*8+0] = wbar;
        stats[p*8+1] = bbar;
        stats[p*8+2] = sww * (1.f/128.f) - wbar*wbar;
        stats[p*8+3] = swb * (1.f/128.f) - wbar*bbar;
        stats[p*8+4] = sbb * (1.f/128.f) - bbar*bbar;
    }
}

// ---------------------------------------------------------------- k1: radial MLP
// grid (384, 4): 64 edges per block, pair = blockIdx.y. 128 threads.
__global__ __launch_bounds__(128) void k1_mlp(
    const float* __restrict__ rel,
    const float* __restrict__ w1, const float* __restrict__ b1,
    const float* __restrict__ g1, const float* __restrict__ be1,
    const float* __restrict__ w2, const float* __restrict__ b2,
    const float* __restrict__ g2, const float* __restrict__ be2,
    const float* __restrict__ stats, float* __restrict__ h2out)
{
    const int p  = blockIdx.y;
    const int e0 = blockIdx.x * 64;
    const int t  = threadIdx.x;
    __shared__ __align__(16) float h1T[128*68];   // [cin][edge], stride 68 (16B-aligned rows)
    __shared__ float dsh[64];
    __shared__ float redS[64*16];
    __shared__ float redQ[64*16];
    __shared__ float muA[64], rsA[64];

    if (t < 64) dsh[t] = rel[e0 + t];
    __syncthreads();

    // phase 1: h1 = relu(LN(d*w1+b1)) via analytic LN stats. thread t = cin.
    {
        const float w  = w1[p*128 + t];
        const float b  = b1[p*128 + t];
        const float g  = g1[p*128 + t];
        const float be = be1[p*128 + t];
        const float wbar = stats[p*8+0], bbar = stats[p*8+1];
        const float Cw = stats[p*8+2], Cwb = stats[p*8+3], Cb = stats[p*8+4];
        #pragma unroll 4
        for (int e = 0; e < 64; ++e) {
            const float d   = dsh[e];
            const float mu  = fmaf(d, wbar, bbar);
            const float var = fmaf(d*d, Cw, fmaf(2.f*d, Cwb, Cb));
            const float y   = fmaf((fmaf(d, w, b) - mu) * rsqrtf(var + EPSV), g, be);
            h1T[t*68 + e] = fmaxf(y, 0.f);
        }
    }
    __syncthreads();

    // phase 2: h2pre = h1 @ w2 + b2 ; 8 edges x 8 couts per thread.
    const int eb = (t & 7) * 8;
    const int cb = (t >> 3) * 8;
    float acc[8][8];
    #pragma unroll
    for (int a = 0; a < 8; ++a)
        #pragma unroll
        for (int c = 0; c < 8; ++c) acc[a][c] = 0.f;

    const float* __restrict__ w2p = w2 + p*16384;
    for (int k = 0; k < 128; ++k) {
        const float4 a0 = *(const float4*)(h1T + k*68 + eb);
        const float4 a1 = *(const float4*)(h1T + k*68 + eb + 4);
        const float4 v0 = *(const float4*)(w2p + k*128 + cb);
        const float4 v1 = *(const float4*)(w2p + k*128 + cb + 4);
        const float av[8] = {a0.x,a0.y,a0.z,a0.w,a1.x,a1.y,a1.z,a1.w};
        const float wv[8] = {v0.x,v0.y,v0.z,v0.w,v1.x,v1.y,v1.z,v1.w};
        #pragma unroll
        for (int ee = 0; ee < 8; ++ee)
            #pragma unroll
            for (int cc = 0; cc < 8; ++cc)
                acc[ee][cc] = fmaf(av[ee], wv[cc], acc[ee][cc]);
    }
    {   // + b2
        const float4 bv0 = *(const float4*)(b2 + p*128 + cb);
        const float4 bv1 = *(const float4*)(b2 + p*128 + cb + 4);
        const float bv[8] = {bv0.x,bv0.y,bv0.z,bv0.w,bv1.x,bv1.y,bv1.z,bv1.w};
        #pragma unroll
        for (int ee = 0; ee < 8; ++ee)
            #pragma unroll
            for (int cc = 0; cc < 8; ++cc) acc[ee][cc] += bv[cc];
    }
    // LN2 reduction: partial sum/sumsq per edge
    #pragma unroll
    for (int ee = 0; ee < 8; ++ee) {
        float s = 0.f, q = 0.f;
        #pragma unroll
        for (int cc = 0; cc < 8; ++cc) { s += acc[ee][cc]; q += acc[ee][cc]*acc[ee][cc]; }
        redS[(eb+ee)*16 + (t>>3)] = s;
        redQ[(eb+ee)*16 + (t>>3)] = q;
    }
    __syncthreads();
    if (t < 64) {
        float s = 0.f, q = 0.f;
        #pragma unroll
        for (int k2 = 0; k2 < 16; ++k2) { s += redS[t*16+k2]; q += redQ[t*16+k2]; }
        const float mu  = s * (1.f/128.f);
        const float var = fmaf(-mu, mu, q * (1.f/128.f));
        muA[t] = mu;
        rsA[t] = rsqrtf(var + EPSV);
    }
    __syncthreads();
    {
        const float4 gv0 = *(const float4*)(g2 + p*128 + cb);
        const float4 gv1 = *(const float4*)(g2 + p*128 + cb + 4);
        const float4 hv0 = *(const float4*)(be2 + p*128 + cb);
        const float4 hv1 = *(const float4*)(be2 + p*128 + cb + 4);
        const float gv[8]  = {gv0.x,gv0.y,gv0.z,gv0.w,gv1.x,gv1.y,gv1.z,gv1.w};
        const float bev[8] = {hv0.x,hv0.y,hv0.z,hv0.w,hv1.x,hv1.y,hv1.z,hv1.w};
        #pragma unroll
        for (int ee = 0; ee < 8; ++ee) {
            const float mu = muA[eb+ee], rs = rsA[eb+ee];
            float o[8];
            #pragma unroll
            for (int cc = 0; cc < 8; ++cc)
                o[cc] = fmaxf(fmaf((acc[ee][cc] - mu) * rs, gv[cc], bev[cc]), 0.f);
            float* dst = h2out + ((size_t)(p*EE) + e0 + eb + ee) * 128 + cb;
            *(float4*)(dst)     = make_float4(o[0],o[1],o[2],o[3]);
            *(float4*)(dst + 4) = make_float4(o[4],o[5],o[6],o[7]);
        }
    }
}

// ---------------------------------------------------------------- k_init: self-interaction
__global__ __launch_bounds__(256) void k_init(
    const float* __restrict__ x0, const float* __restrict__ x1,
    const float* __restrict__ ks0, const float* __restrict__ ks1,
    float* __restrict__ out)
{
    const int gid = blockIdx.x * 256 + threadIdx.x;    // 32768 = 512*16*4
    const int d = gid & 3, o = (gid >> 2) & 15, n = gid >> 6;
    float acc = 0.f;
    if (d == 0) {
        #pragma unroll
        for (int i = 0; i < 16; ++i) acc += ks0[o*16+i] * x0[n*16+i];
    } else {
        const int u = d - 1;
        #pragma unroll
        for (int i = 0; i < 16; ++i) acc += ks1[o*16+i] * x1[(n*16+i)*3 + u];
    }
    out[gid] = acc;
}

// ---------------------------------------------------------------- k2: per-n fused S-GEMM + w3 contraction
template<int DI, int DO>
__global__ __launch_bounds__(256) void k2_pair(
    const float* __restrict__ xsrc,            // x0 if DI==0 else x1
    const int* __restrict__ nidx,
    const void* __restrict__ nmaskv,           // dtype per stats[30] flag
    const float* __restrict__ basis,
    const float* __restrict__ w3,
    const float* __restrict__ b3,
    const float* __restrict__ h2ws,
    const float* __restrict__ stats,
    float* __restrict__ out)
{
    constexpr int V  = 2*DI + 1;
    constexpr int U  = 2*DO + 1;
    constexpr int F  = 2*(DI < DO ? DI : DO) + 1;
    constexpr int KF = 16*F;            // k = i*F+f range per o
    constexpr int Q  = 16*U*F;          // q = u*KF + k
    constexpr int QS = Q + 4;           // padded row (keeps 16B alignment, breaks pow2 stride)
    constexpr int BP = U*V*F;           // basis elems per edge
    constexpr int P  = 2*DI + DO;       // pair index in PAIRS order
    constexpr int XW = 16*V;            // gathered row width

    const int n = blockIdx.x;
    const int t = threadIdx.x;

    __shared__ __align__(16) float Em[JJ*QS];
    __shared__ __align__(16) float regB[JJ*132];   // phase A: xg+basis; phase B: h2aug [48][132]
    __shared__ float tailAcc[16*U];
    __shared__ float sDenomInv;
    __shared__ int   idxL[JJ];
    __shared__ float mjf[JJ];

    float* xg   = regB;              // [48][16V]
    float* basL = regB + JJ*XW;      // [48][BP]
    float* h2L  = regB;              // [48][132], col 128 = 1.0 (b3 row), 129..131 = 0

    if (t < 16*U) tailAcc[t] = 0.f;
    if (t < JJ) {
        idxL[t] = nidx[n*JJ + t];
        const int useU8 = (stats[30] != 0.f);
        const int mv = useU8 ? (int)((const unsigned char*)nmaskv)[n*JJ + t]
                             : ((const int*)nmaskv)[n*JJ + t];
        mjf[t] = mv ? 1.f : 0.f;
    }
    __syncthreads();

    if (t == 0) {
        float s = 0.f;
        for (int j = 0; j < JJ; ++j) s += mjf[j];
        sDenomInv = 1.f / s;                       // mask[...,0]=True guarantees s>=1
    }
    // gather neighbor features + basis
    for (int e = t; e < JJ*XW; e += 256) {
        const int j = e / XW, r = e % XW;
        xg[e] = xsrc[idxL[j]*XW + r];
    }
    for (int e = t; e < JJ*BP; e += 256)
        basL[e] = basis[n*JJ*BP + e];
    __syncthreads();

    // Em[j][u*KF + i*F + f] = m_j * sum_v basis[j][(u*V+v)*F+f] * xg[j][i*V+v]
    for (int e = t; e < JJ*Q; e += 256) {
        const int j = e / Q, q = e % Q;
        const int u = q / KF, k = q % KF, i = k / F, f = k % F;
        float a = 0.f;
        #pragma unroll
        for (int v = 0; v < V; ++v)
            a = fmaf(basL[j*BP + (u*V + v)*F + f], xg[j*XW + i*V + v], a);
        Em[j*QS + q] = mjf[j] * a;
    }
    __syncthreads();

    // load h2 rows (overwrites xg/basis region)
    for (int e = t; e < JJ*132; e += 256) {
        const int j = e / 132, c = e % 132;
        float v;
        if (c < 128)      v = h2ws[((size_t)(P*EE + n*JJ + j))*128 + c];
        else if (c == 128) v = 1.f;
        else               v = 0.f;
        h2L[e] = v;
    }
    __syncthreads();

    // fused S-GEMM (K=48) + w3 contraction. Task = (ct, qt): 4 c-rows x 8 q-cols.
    constexpr int CT = 33;              // 132/4 c-tiles (rows 129..131 are zero)
    constexpr int QT = Q / 8;
    constexpr int NT = CT * QT;
    for (int task = t; task < NT; task += 256) {
        const int qt = task % QT;       // adjacent lanes -> adjacent q (coalesced w3 reads)
        const int ct = task / QT;
        const int c0 = ct * 4, q0 = qt * 8;
        const int u  = q0 / KF, k0 = q0 % KF;

        float sacc[4][8];
        #pragma unroll
        for (int a = 0; a < 4; ++a)
            #pragma unroll
            for (int b = 0; b < 8; ++b) sacc[a][b] = 0.f;

        for (int j = 0; j < JJ; ++j) {
            const float4 h  = *(const float4*)(h2L + j*132 + c0);
            const float4 ea = *(const float4*)(Em + j*QS + q0);
            const float4 eb = *(const float4*)(Em + j*QS + q0 + 4);
            const float hv[4] = {h.x, h.y, h.z, h.w};
            const float ev[8] = {ea.x,ea.y,ea.z,ea.w,eb.x,eb.y,eb.z,eb.w};
            #pragma unroll
            for (int cc = 0; cc < 4; ++cc)
                #pragma unroll
                for (int qq = 0; qq < 8; ++qq)
                    sacc[cc][qq] = fmaf(hv[cc], ev[qq], sacc[cc][qq]);
        }

        float po[16];
        #pragma unroll
        for (int o = 0; o < 16; ++o) po[o] = 0.f;
        #pragma unroll
        for (int cc = 0; cc < 4; ++cc) {
            const int c = c0 + cc;
            if (c > 128) continue;
            const float* wrow = (c < 128) ? (w3 + (size_t)c * (16*KF)) : b3;
            #pragma unroll
            for (int o = 0; o < 16; ++o) {
                const float4 wa = *(const float4*)(wrow + o*KF + k0);
                const float4 wb = *(const float4*)(wrow + o*KF + k0 + 4);
                po[o] += wa.x*sacc[cc][0] + wa.y*sacc[cc][1] + wa.z*sacc[cc][2] + wa.w*sacc[cc][3]
                       + wb.x*sacc[cc][4] + wb.y*sacc[cc][5] + wb.z*sacc[cc][6] + wb.w*sacc[cc][7];
            }
        }
        #pragma unroll
        for (int o = 0; o < 16; ++o) atomicAdd(&tailAcc[o*U + u], po[o]);
    }
    __syncthreads();

    if (t < 16*U) {
        const int o = t / U, u = t % U;
        const float val = tailAcc[t] * sDenomInv;
        const int d = (DO == 0) ? 0 : (1 + u);
        atomicAdd(&out[(n*16 + o)*4 + d], val);
    }
}

// ---------------------------------------------------------------- launch
extern "C" void kernel_launch(void* const* d_in, const int* in_sizes, int n_in,
                              void* d_out, int out_size, void* d_ws, size_t ws_size,
                              hipStream_t stream)
{
    const float* x0    = (const float*)d_in[0];
    const float* x1    = (const float*)d_in[1];
    const float* rel   = (const float*)d_in[2];
    const int*   nidx  = (const int*)d_in[3];
    const void*  nmask = d_in[4];
    const float* basis00 = (const float*)d_in[5];
    const float* basis01 = (const float*)d_in[6];
    const float* basis10 = (const float*)d_in[7];
    const float* basis11 = (const float*)d_in[8];
    const float* w1  = (const float*)d_in[9];
    const float* b1  = (const float*)d_in[10];
    const float* g1  = (const float*)d_in[11];
    const float* be1 = (const float*)d_in[12];
    const float* w2  = (const float*)d_in[13];
    const float* b2  = (const float*)d_in[14];
    const float* g2  = (const float*)d_in[15];
    const float* be2 = (const float*)d_in[16];
    const float* w3_00 = (const float*)d_in[17];
    const float* b3_00 = (const float*)d_in[18];
    const float* w3_01 = (const float*)d_in[19];
    const float* b3_01 = (const float*)d_in[20];
    const float* w3_10 = (const float*)d_in[21];
    const float* b3_10 = (const float*)d_in[22];
    const float* w3_11 = (const float*)d_in[23];
    const float* b3_11 = (const float*)d_in[24];
    const float* ks0 = (const float*)d_in[25];
    const float* ks1 = (const float*)d_in[26];
    float* out = (float*)d_out;

    // workspace: h2 fp32 [4][E][128] = 50.33 MB, then LN1 stats (32 floats)
    float* h2ws  = (float*)d_ws;
    float* stats = h2ws + (size_t)4*EE*128;

    k0_stats<<<2, 256, 0, stream>>>(w1, b1, nmask, stats);
    k1_mlp<<<dim3(384, 4), 128, 0, stream>>>(rel, w1, b1, g1, be1, w2, b2, g2, be2, stats, h2ws);
    k_init<<<128, 256, 0, stream>>>(x0, x1, ks0, ks1, out);
    k2_pair<0,0><<<NN, 256, 0, stream>>>(x0, nidx, nmask, basis00, w3_00, b3_00, h2ws, stats, out);
    k2_pair<0,1><<<NN, 256, 0, stream>>>(x0, nidx, nmask, basis01, w3_01, b3_01, h2ws, stats, out);
    k2_pair<1,0><<<NN, 256, 0, stream>>>(x1, nidx, nmask, basis10, w3_10, b3_10, h2ws, stats, out);
    k2_pair<1,1><<<NN, 256, 0, stream>>>(x1, nidx, nmask, basis11, w3_11, b3_11, h2ws, stats, out);
}